// Round 13
// baseline (507.021 us; speedup 1.0000x reference)
//
#include <hip/hip_runtime.h>
#include <math.h>

#define N_NODES 131072
#define N_EDGES 262144
#define N_B     4096
// NODE_DIM=16, EDGE_DIM=4, HIDDEN=64, MLP_HID=128

typedef __attribute__((ext_vector_type(8))) short short8;
typedef __attribute__((ext_vector_type(4))) float f32x4;
typedef __attribute__((ext_vector_type(16))) float f32x16;

__device__ __forceinline__ float fast_sig(float x) {
    return 1.0f / (1.0f + __expf(-x));
}
__device__ __forceinline__ float fast_tanh(float x) {
    float t = __expf(-2.0f * fabsf(x));
    float r = (1.0f - t) / (1.0f + t);
    return copysignf(r, x);
}

// round-to-nearest-even fp32 -> bf16 (bit trick), plus residual split
__device__ __forceinline__ unsigned short bf16_rne(float v) {
    unsigned u = __float_as_uint(v);
    u += 0x7FFFu + ((u >> 16) & 1u);
    return (unsigned short)(u >> 16);
}
__device__ __forceinline__ void split_bf16(float v, short& hi, short& lo) {
    unsigned short h = bf16_rne(v);
    float hf = __uint_as_float((unsigned)h << 16);
    unsigned short l = bf16_rne(v - hf);
    hi = (short)h; lo = (short)l;
}

// -------- merged prep kernel: blockIdx ranges dispatch the 4 prep jobs -----
__global__ __launch_bounds__(256) void k_misc(
    const float* __restrict__ we2, unsigned short* __restrict__ wt,
    const float* __restrict__ gwih, const float* __restrict__ gwhh,
    const float* __restrict__ gbih, const float* __restrict__ gbhh,
    unsigned short* __restrict__ wtg, float* __restrict__ gbias,
    const float* __restrict__ lwih, const float* __restrict__ lwhh,
    float4* __restrict__ wA, float4* __restrict__ wB,
    const int* __restrict__ batch, int* __restrict__ starts)
{
    const int bid = blockIdx.x;
    const int tid = threadIdx.x;
    if (bid < 64) {
        // ---- prep_w: wt[d(16)][u(2)][s(8)][hl(2)][lane(64)][j(8)] ----
        int p = bid * 256 + tid;  // [0, 16384)
        int d = p >> 10;
        int u = (p >> 9) & 1;
        int s = (p >> 6) & 7;
        int l = p & 63;
        int k0 = s * 16 + ((l >> 5) << 3);
        int h = u * 32 + (l & 31);
        short8 hv, lv;
        #pragma unroll
        for (int j = 0; j < 8; ++j) {
            float v = we2[(size_t)(k0 + j) * 1024 + d * 64 + h];
            short hi, lo; split_bf16(v, hi, lo);
            hv[j] = hi; lv[j] = lo;
        }
        size_t base = (size_t)d * 16384 + (size_t)u * 8192 + s * 1024 + l * 8;
        *(short8*)&wt[base] = hv;
        *(short8*)&wt[base + 512] = lv;
    } else if (bid < 72) {
        // ---- prep_gru ----
        int p = (bid - 64) * 256 + tid;  // [0, 2048)
        if (p < 256) {
            int g = p >> 6, j = p & 63;
            float b;
            if (g == 0)      b = gbih[j] + gbhh[j];
            else if (g == 1) b = gbih[64 + j] + gbhh[64 + j];
            else if (g == 2) b = gbih[128 + j];
            else             b = gbhh[128 + j];
            gbias[p] = b;
        }
        int u = p >> 7, ks = (p >> 6) & 1, ln = p & 63;
        int n = u * 16 + (ln & 15);
        int g = n >> 6, jn = n & 63;
        int k0 = ks * 32 + (ln >> 4) * 8;
        short8 hv, lv;
        #pragma unroll
        for (int jj = 0; jj < 8; ++jj) {
            int k = k0 + jj;
            float v;
            if (g == 0)      v = gwih[jn * 64 + k] + gwhh[jn * 64 + k];
            else if (g == 1) v = gwih[(64 + jn) * 64 + k] + gwhh[(64 + jn) * 64 + k];
            else if (g == 2) v = gwih[(128 + jn) * 64 + k];
            else             v = gwhh[(128 + jn) * 64 + k];
            short hi, lo; split_bf16(v, hi, lo);
            hv[jj] = hi; lv[jj] = lo;
        }
        size_t base = (size_t)(u * 2 + ks) * 1024 + ln * 8;
        *(short8*)&wtg[base] = hv;
        *(short8*)&wtg[base + 512] = lv;
    } else if (bid < 88) {
        // ---- prep_lstm: wA merges wih[:, :64]+whh (q_prev==h_prev) ----
        int p = (bid - 72) * 256 + tid;  // [0, 4096)
        int k = p >> 6, ln = p & 63;
        float4 a, b;
        a.x = lwih[(0 * 64 + ln) * 128 + k] + lwhh[(0 * 64 + ln) * 64 + k];
        a.y = lwih[(1 * 64 + ln) * 128 + k] + lwhh[(1 * 64 + ln) * 64 + k];
        a.z = lwih[(2 * 64 + ln) * 128 + k] + lwhh[(2 * 64 + ln) * 64 + k];
        a.w = lwih[(3 * 64 + ln) * 128 + k] + lwhh[(3 * 64 + ln) * 64 + k];
        b.x = lwih[(0 * 64 + ln) * 128 + 64 + k];
        b.y = lwih[(1 * 64 + ln) * 128 + 64 + k];
        b.z = lwih[(2 * 64 + ln) * 128 + 64 + k];
        b.w = lwih[(3 * 64 + ln) * 128 + 64 + k];
        wA[p] = a; wB[p] = b;
    } else {
        // ---- starts ----
        int g = (bid - 88) * 256 + tid;
        if (g > N_B) return;
        if (g == N_B) { starts[N_B] = N_NODES; return; }
        int lo = 0, hi = N_NODES;
        while (lo < hi) {
            int mid = (lo + hi) >> 1;
            if (batch[mid] < g) lo = mid + 1; else hi = mid;
        }
        starts[g] = lo;
    }
}

// -------- fused edge MLP + 32x32x16 MFMA message GEMM + atomic scatter -----
// (round-9 proven structure; launched as 2 half-range dispatches so that
// hidden kernels >~112us surface in the rocprof top-5 with full counters)
__global__ __launch_bounds__(256, 2) void k_edge(
    const float* __restrict__ x,     // [N,16]
    const float* __restrict__ ea,    // [E,4]
    const int*   __restrict__ eidx,  // [2,E]
    const float* __restrict__ we1,   // [4,128]
    const float* __restrict__ be1,   // [128]
    const unsigned short* __restrict__ wt,  // pre-split we2 frags
    const float* __restrict__ be2,   // [1024]
    float* __restrict__ msum,        // [N,64]
    float* __restrict__ cnt,         // [N]
    int blk0)                        // block-index offset for this dispatch
{
    __shared__ unsigned short sAh[16384];  // [mt(4)][s(8)][lane(64)][j(8)] 32KB
    __shared__ unsigned short sAl[16384];  // 32KB
    __shared__ float sx[128 * 16];         // 8KB
    __shared__ float sbe2[1024];           // 4KB
    __shared__ int   sdst[128];

    const int tid = threadIdx.x;
    const int w   = tid >> 6;        // wave
    const int ln  = tid & 63;        // lane
    const int u     = w >> 1;        // n-tile (cols u*32..u*32+31)
    const int mbase = (w & 1) * 2;   // first of 2 m-tiles
    const int blk = blockIdx.x + blk0;
    const int eb  = blk * 128;

    if (tid < 128) sdst[tid] = eidx[N_EDGES + eb + tid];
    #pragma unroll
    for (int v = tid; v < 1024; v += 256) sbe2[v] = be2[v];

    #pragma unroll
    for (int v = tid; v < 512; v += 256) {
        int e = v >> 2, q = v & 3;
        int src = eidx[eb + e];
        float4 t4 = ((const float4*)(x + (size_t)src * 16))[q];
        ((float4*)sx)[e * 4 + q] = t4;
    }

    // ---- h1 = relu(ea @ we1 + be1), split bf16 hi/lo, 32x32 A-frag layout --
    #pragma unroll 1
    for (int i = 0; i < 8; ++i) {
        int cc = tid + i * 256;          // [0,2048): [mt(4)][s(8)][l(64)]
        int mt = cc >> 9;
        int s  = (cc >> 6) & 7;
        int l  = cc & 63;
        int e   = mt * 32 + (l & 31);
        int kk0 = s * 16 + ((l >> 5) << 3);
        float4 eav = *(const float4*)(ea + (size_t)(eb + e) * 4);
        float4 b0 = *(const float4*)(be1 + kk0);
        float4 b1 = *(const float4*)(be1 + kk0 + 4);
        float acc[8] = {b0.x, b0.y, b0.z, b0.w, b1.x, b1.y, b1.z, b1.w};
        #pragma unroll
        for (int a = 0; a < 4; ++a) {
            float4 wa0 = *(const float4*)(we1 + a * 128 + kk0);
            float4 wa1 = *(const float4*)(we1 + a * 128 + kk0 + 4);
            float ev = (a == 0) ? eav.x : (a == 1) ? eav.y : (a == 2) ? eav.z : eav.w;
            acc[0] += ev * wa0.x; acc[1] += ev * wa0.y;
            acc[2] += ev * wa0.z; acc[3] += ev * wa0.w;
            acc[4] += ev * wa1.x; acc[5] += ev * wa1.y;
            acc[6] += ev * wa1.z; acc[7] += ev * wa1.w;
        }
        short8 hv, lv;
        #pragma unroll
        for (int j = 0; j < 8; ++j) {
            float v = fmaxf(acc[j], 0.0f);
            short hi, lo; split_bf16(v, hi, lo);
            hv[j] = hi; lv[j] = lo;
        }
        *(short8*)&sAh[cc * 8] = hv;
        *(short8*)&sAl[cc * 8] = lv;
    }
    __syncthreads();   // the ONLY barrier

    // ---- hoist A fragments (compiler keeps hot subset in regs) ----
    short8 ah[2][8], al[2][8];
    #pragma unroll
    for (int m2 = 0; m2 < 2; ++m2) {
        int mt = mbase + m2;
        #pragma unroll
        for (int s = 0; s < 8; ++s) {
            ah[m2][s] = *(short8*)&sAh[((mt * 8 + s) * 64 + ln) * 8];
            al[m2][s] = *(short8*)&sAl[((mt * 8 + s) * 64 + ln) * 8];
        }
    }

    // ---- main loop over d (rotated start); B ring-4, prefetch distance 3 --
    const unsigned short* wdu = wt + (size_t)u * 8192;
    const int d0 = blk & 15;
    const int rbase = (ln >> 5) * 4;

    f32x16 msg[2];
    #pragma unroll
    for (int r = 0; r < 16; ++r) { msg[0][r] = 0.0f; msg[1][r] = 0.0f; }

    short8 bh[4], bl[4];
    {   // preload flat steps 0,1,2 of (d0, s)
        const unsigned short* p0 = wdu + (size_t)d0 * 16384 + ln * 8;
        bh[0] = *(const short8*)p0;            bl[0] = *(const short8*)(p0 + 512);
        bh[1] = *(const short8*)(p0 + 1024);   bl[1] = *(const short8*)(p0 + 1536);
        bh[2] = *(const short8*)(p0 + 2048);   bl[2] = *(const short8*)(p0 + 2560);
    }

    #pragma unroll 1
    for (int dd = 0; dd < 16; ++dd) {
        const int d = (d0 + dd) & 15;
        const unsigned short* wd  = wdu + (size_t)d * 16384;
        const unsigned short* wnx = wdu + (size_t)((d + 1) & 15) * 16384;

        float bv = sbe2[d * 64 + u * 32 + (ln & 31)];
        f32x16 c2[2];
        #pragma unroll
        for (int r = 0; r < 16; ++r) { c2[0][r] = bv; c2[1][r] = bv; }

        #pragma unroll
        for (int s = 0; s < 8; ++s) {
            const int cur = s & 3;
            const int pf  = (s + 3) & 3;   // slot freed last step
            if (s < 5) {
                const unsigned short* p = wd + (s + 3) * 1024 + ln * 8;
                bh[pf] = *(const short8*)p;
                bl[pf] = *(const short8*)(p + 512);
            } else if (dd < 15) {
                const unsigned short* p = wnx + (s - 5) * 1024 + ln * 8;
                bh[pf] = *(const short8*)p;
                bl[pf] = *(const short8*)(p + 512);
            }
            c2[0] = __builtin_amdgcn_mfma_f32_32x32x16_bf16(ah[0][s], bh[cur], c2[0], 0, 0, 0);
            c2[1] = __builtin_amdgcn_mfma_f32_32x32x16_bf16(ah[1][s], bh[cur], c2[1], 0, 0, 0);
            c2[0] = __builtin_amdgcn_mfma_f32_32x32x16_bf16(ah[0][s], bl[cur], c2[0], 0, 0, 0);
            c2[1] = __builtin_amdgcn_mfma_f32_32x32x16_bf16(ah[1][s], bl[cur], c2[1], 0, 0, 0);
            c2[0] = __builtin_amdgcn_mfma_f32_32x32x16_bf16(al[0][s], bh[cur], c2[0], 0, 0, 0);
            c2[1] = __builtin_amdgcn_mfma_f32_32x32x16_bf16(al[1][s], bh[cur], c2[1], 0, 0, 0);
        }
        // epilogue: msg += x[:,d] * C_d   (C row = (reg&3)+8*(reg>>2)+rbase)
        #pragma unroll
        for (int m2 = 0; m2 < 2; ++m2) {
            #pragma unroll
            for (int r = 0; r < 16; ++r) {
                int row = (r & 3) + ((r >> 2) * 8) + rbase;
                float xv = sx[((mbase + m2) * 32 + row) * 16 + d];
                msg[m2][r] = fmaf(xv, c2[m2][r], msg[m2][r]);
            }
        }
    }

    // ---- scatter ----
    const int col = u * 32 + (ln & 31);
    #pragma unroll
    for (int m2 = 0; m2 < 2; ++m2) {
        #pragma unroll
        for (int r = 0; r < 16; ++r) {
            int row = (r & 3) + ((r >> 2) * 8) + rbase;
            int dst = sdst[(mbase + m2) * 32 + row];
            atomicAdd(msum + (size_t)dst * 64 + col, msg[m2][r]);
        }
    }
    if (u == 0 && (ln & 31) == 0) {
        #pragma unroll
        for (int m2 = 0; m2 < 2; ++m2) {
            #pragma unroll
            for (int r = 0; r < 16; ++r) {
                int row = (r & 3) + ((r >> 2) * 8) + rbase;
                atomicAdd(&cnt[sdst[(mbase + m2) * 32 + row]], 1.0f);
            }
        }
    }
}

// -------- fused combine + 3-step GRU via in-block MFMA GEMM --------
// 128 nodes/block (was 256): LDS ~37.5KB -> 4 blocks/CU = 4 waves/SIMD,
// doubling latency hiding for this latency/VALU-bound kernel.
__global__ __launch_bounds__(256) void k_gru2(
    float* __restrict__ buf,        // [N,64] in: msum; out: final h
    const float* __restrict__ cnt,  // [N]
    const float* __restrict__ x,    // [N,16]
    const float* __restrict__ root, // [16,64]
    const float* __restrict__ cb,   // [64]
    const unsigned short* __restrict__ wtg,  // [16][2][2][64][8] ushort
    const float* __restrict__ gbias)         // [256]
{
    __shared__ unsigned short sAh[8192];   // [mt(8)][ks(2)][lane(64)][j(8)] 16KB
    __shared__ unsigned short sAl[8192];   // 16KB
    __shared__ float sroot[1024];
    __shared__ float sbias[256];
    __shared__ float scb[64];
    const int tid = threadIdx.x;
    const int w = tid >> 6, ln = tid & 63, lq = ln >> 4, lm = ln & 15;
    const size_t nbase = (size_t)blockIdx.x * 128;

    #pragma unroll
    for (int v = tid; v < 1024; v += 256) sroot[v] = root[v];
    sbias[tid] = gbias[tid];
    if (tid < 64) scb[tid] = cb[tid];
    __syncthreads();

    // ---- initial A build: combine (msum/cnt + x@root + cb, relu) fused ----
    #pragma unroll 1
    for (int i = 0; i < 4; ++i) {
        int cc = tid + i * 256;            // [0,1024): [mt(8)][ks(2)][l(64)]
        int mt = cc >> 7, ks = (cc >> 6) & 1, l = cc & 63;
        size_t gn = nbase + mt * 16 + (l & 15);
        int c0 = ks * 32 + (l >> 4) * 8;
        float4 m0 = *(const float4*)(buf + gn * 64 + c0);
        float4 m1 = *(const float4*)(buf + gn * 64 + c0 + 4);
        float cinv = 1.0f / fmaxf(cnt[gn], 1.0f);
        float xv[16];
        *(float4*)&xv[0]  = *(const float4*)(x + gn * 16);
        *(float4*)&xv[4]  = *(const float4*)(x + gn * 16 + 4);
        *(float4*)&xv[8]  = *(const float4*)(x + gn * 16 + 8);
        *(float4*)&xv[12] = *(const float4*)(x + gn * 16 + 12);
        float acc[8];
        #pragma unroll
        for (int j = 0; j < 8; ++j) acc[j] = scb[c0 + j];
        #pragma unroll
        for (int d = 0; d < 16; ++d) {
            float xd = xv[d];
            #pragma unroll
            for (int j = 0; j < 8; ++j) acc[j] += xd * sroot[d * 64 + c0 + j];
        }
        float ms[8] = {m0.x, m0.y, m0.z, m0.w, m1.x, m1.y, m1.z, m1.w};
        short8 hv, lv;
        #pragma unroll
        for (int j = 0; j < 8; ++j) {
            float hval = fmaxf(ms[j] * cinv + acc[j], 0.0f);
            short hi, lo; split_bf16(hval, hi, lo);
            hv[j] = hi; lv[j] = lo;
        }
        *(short8*)&sAh[cc * 8] = hv;
        *(short8*)&sAl[cc * 8] = lv;
    }
    __syncthreads();

    float hreg[4][2][4];  // [v][i][reg] old h in C-layout, carried across steps
    #pragma unroll 1
    for (int step = 0; step < 3; ++step) {
        short8 ah[2][2], al[2][2];
        #pragma unroll
        for (int i = 0; i < 2; ++i)
            #pragma unroll
            for (int ks = 0; ks < 2; ++ks) {
                int mt = w * 2 + i;
                ah[i][ks] = *(short8*)&sAh[((mt * 2 + ks) * 64 + ln) * 8];
                al[i][ks] = *(short8*)&sAl[((mt * 2 + ks) * 64 + ln) * 8];
            }
        if (step == 0) {   // old-h at this lane's C positions, once
            #pragma unroll
            for (int v = 0; v < 4; ++v) {
                int ksp = v >> 1;
                int lq2 = (v & 1) * 2 + (lm >> 3);
                int jp = lm & 7;
                #pragma unroll
                for (int i = 0; i < 2; ++i) {
                    int mt = w * 2 + i;
                    #pragma unroll
                    for (int r = 0; r < 4; ++r) {
                        int idx = ((mt * 2 + ksp) * 64 + lq2 * 16 + lq * 4 + r) * 8 + jp;
                        float hi = __uint_as_float((unsigned)sAh[idx] << 16);
                        float lo = __uint_as_float((unsigned)sAl[idx] << 16);
                        hreg[v][i][r] = hi + lo;
                    }
                }
            }
        }
        __syncthreads();   // all reads done before any epilogue write

        #pragma unroll 1
        for (int v = 0; v < 4; ++v) {
            f32x4 C[4][2];  // [gate g][m-tile i]
            #pragma unroll
            for (int g = 0; g < 4; ++g) {
                float bv = sbias[g * 64 + v * 16 + lm];
                #pragma unroll
                for (int i = 0; i < 2; ++i) C[g][i] = (f32x4){bv, bv, bv, bv};
            }
            #pragma unroll
            for (int g = 0; g < 4; ++g) {
                int u = g * 4 + v;
                #pragma unroll
                for (int ks = 0; ks < 2; ++ks) {
                    size_t wb = (size_t)(u * 2 + ks) * 1024 + ln * 8;
                    short8 bh = *(const short8*)&wtg[wb];
                    short8 bl = *(const short8*)&wtg[wb + 512];
                    #pragma unroll
                    for (int i = 0; i < 2; ++i) {
                        C[g][i] = __builtin_amdgcn_mfma_f32_16x16x32_bf16(ah[i][ks], bh, C[g][i], 0, 0, 0);
                        C[g][i] = __builtin_amdgcn_mfma_f32_16x16x32_bf16(ah[i][ks], bl, C[g][i], 0, 0, 0);
                        C[g][i] = __builtin_amdgcn_mfma_f32_16x16x32_bf16(al[i][ks], bh, C[g][i], 0, 0, 0);
                    }
                }
            }
            int ksp = v >> 1;
            int lq2 = (v & 1) * 2 + (lm >> 3);
            int jp = lm & 7;
            #pragma unroll
            for (int i = 0; i < 2; ++i) {
                int mt = w * 2 + i;
                #pragma unroll
                for (int r = 0; r < 4; ++r) {
                    float rr = fast_sig(C[0][i][r]);
                    float zz = fast_sig(C[1][i][r]);
                    float nn = fast_tanh(C[2][i][r] + rr * C[3][i][r]);
                    float hnew = (1.0f - zz) * nn + zz * hreg[v][i][r];
                    hreg[v][i][r] = hnew;
                    if (step < 2) {
                        short hi, lo; split_bf16(hnew, hi, lo);
                        int idx = ((mt * 2 + ksp) * 64 + lq2 * 16 + lq * 4 + r) * 8 + jp;
                        sAh[idx] = (unsigned short)hi;
                        sAl[idx] = (unsigned short)lo;
                    } else {
                        buf[(nbase + mt * 16 + lq * 4 + r) * 64 + v * 16 + lm] = hnew;
                    }
                }
            }
        }
        if (step < 2) __syncthreads();
    }
}

// -------- Set2Set (3 steps) + final MLP; wave-per-graph, 4 graphs/block ----
// All LDS state is wave-private -> NO inter-wave barriers.
__global__ __launch_bounds__(256) void k_s2s(
    const float* __restrict__ out,    // [N,64]
    const int*   __restrict__ starts, // [B+1]
    const float4* __restrict__ wA,    // [64*64] packed gate weights vs h_prev
    const float4* __restrict__ wB,    // [64*64] packed gate weights vs rg_prev
    const float* __restrict__ bih,    // [256]
    const float* __restrict__ bhh,    // [256]
    const float* __restrict__ fc1w,   // [128,64]
    const float* __restrict__ fc1b,   // [64]
    const float* __restrict__ fc2w,   // [64]
    const float* __restrict__ fc2b,   // [1]
    float* __restrict__ y)            // [B]
{
    __shared__ float qsL[4][128];     // [graph][ h(64) | r_g(64) ]
    __shared__ float ebuf[4][256];
    const int tid = threadIdx.x;
    const int wv = tid >> 6, ln = tid & 63;
    const int gid = blockIdx.x * 4 + wv;

    const int s0 = starts[gid];
    int L = starts[gid + 1] - s0; if (L > 256) L = 256;  // P(L>256) ~ 0 (mean 32)

    qsL[wv][ln] = 0.0f; qsL[wv][64 + ln] = 0.0f;
    __builtin_amdgcn_wave_barrier();

    const float b0 = bih[ln] + bhh[ln];
    const float b1 = bih[64 + ln] + bhh[64 + ln];
    const float b2 = bih[128 + ln] + bhh[128 + ln];
    const float b3 = bih[192 + ln] + bhh[192 + ln];

    float c = 0.0f;

    #pragma unroll 1
    for (int step = 0; step < 3; ++step) {
        // ---- gates: lane ln = rows {ln, 64+ln, 128+ln, 192+ln} ----
        float a0 = b0, a1 = b1, a2 = b2, a3 = b3;
        #pragma unroll 4
        for (int k = 0; k < 64; ++k) {
            float qk = qsL[wv][k];          // h_prev[k] (== q_prev[k])
            float rk = qsL[wv][64 + k];     // r_g prev[k]
            float4 wa = wA[k * 64 + ln];    // coalesced
            float4 wb = wB[k * 64 + ln];
            a0 += wa.x * qk + wb.x * rk;
            a1 += wa.y * qk + wb.y * rk;
            a2 += wa.z * qk + wb.z * rk;
            a3 += wa.w * qk + wb.w * rk;
        }
        float ig = fast_sig(a0), fg = fast_sig(a1);
        float gg = fast_tanh(a2), og = fast_sig(a3);
        c = fg * c + ig * gg;
        float h = og * fast_tanh(c);
        __builtin_amdgcn_wave_barrier();
        qsL[wv][ln] = h;                    // new q part (wave-private)
        __builtin_amdgcn_wave_barrier();

        // ---- attention (graph private to this wave) ----
        float m = -1e30f;
        for (int c0 = 0; c0 * 64 < L; ++c0) {
            int j = c0 * 64 + ln;
            if (j < L) {
                const float4* orow = (const float4*)(out + (size_t)(s0 + j) * 64);
                float a = 0.0f;
                #pragma unroll
                for (int l4 = 0; l4 < 16; ++l4) {
                    float4 ov = orow[l4];
                    float4 hv = *(const float4*)&qsL[wv][l4 * 4];
                    a += ov.x * hv.x + ov.y * hv.y + ov.z * hv.z + ov.w * hv.w;
                }
                ebuf[wv][j] = a;
                m = fmaxf(m, a);
            }
        }
        #pragma unroll
        for (int off = 32; off; off >>= 1) m = fmaxf(m, __shfl_xor(m, off));
        float ds = 0.0f;
        for (int c0 = 0; c0 * 64 < L; ++c0) {
            int j = c0 * 64 + ln;
            if (j < L) {
                float ex = __expf(ebuf[wv][j] - m);
                ebuf[wv][j] = ex;
                ds += ex;
            }
        }
        #pragma unroll
        for (int off = 32; off; off >>= 1) ds += __shfl_xor(ds, off);
        __builtin_amdgcn_wave_barrier();
        // r_g[ln] = sum_j a_j * out[s0+j][ln]  (coalesced across lanes)
        float rg = 0.0f;
        for (int j = 0; j < L; ++j)
            rg = fmaf(ebuf[wv][j], out[(size_t)(s0 + j) * 64 + ln], rg);
        rg = (L > 0) ? (rg / ds) : 0.0f;
        qsL[wv][64 + ln] = rg;
        __builtin_amdgcn_wave_barrier();
    }

    // ---- final MLP: u = relu(q_star@fc1 + b); y = u@fc2 + b2 ----
    float a = fc1b[ln];
    #pragma unroll 4
    for (int k = 0; k < 128; ++k)
        a = fmaf(qsL[wv][k], fc1w[k * 64 + ln], a);
    float uu = fmaxf(a, 0.0f) * fc2w[ln];
    #pragma unroll
    for (int off = 32; off; off >>= 1) uu += __shfl_xor(uu, off);
    if (ln == 0) y[gid] = uu + fc2b[0];
}

extern "C" void kernel_launch(void* const* d_in, const int* in_sizes, int n_in,
                              void* d_out, int out_size, void* d_ws, size_t ws_size,
                              hipStream_t stream) {
    const float* x     = (const float*)d_in[0];
    const float* ea    = (const float*)d_in[1];
    const int*   eidx  = (const int*)d_in[2];
    const int*   batch = (const int*)d_in[3];
    const float* we1   = (const float*)d_in[4];
    const float* be1   = (const float*)d_in[5];
    const float* we2   = (const float*)d_in[6];
    const float* be2   = (const float*)d_in[7];
    const float* root  = (const float*)d_in[8];
    const float* cb    = (const float*)d_in[9];
    const float* gwih  = (const float*)d_in[10];
    const float* gwhh  = (const float*)d_in[11];
    const float* gbih  = (const float*)d_in[12];
    const float* gbhh  = (const float*)d_in[13];
    const float* lwih  = (const float*)d_in[14];
    const float* lwhh  = (const float*)d_in[15];
    const float* lbih  = (const float*)d_in[16];
    const float* lbhh  = (const float*)d_in[17];
    const float* fc1w  = (const float*)d_in[18];
    const float* fc1b  = (const float*)d_in[19];
    const float* fc2w  = (const float*)d_in[20];
    const float* fc2b  = (const float*)d_in[21];

    float* buf = (float*)d_ws;                      // [N,64] msum -> h
    float* cnt = buf + (size_t)N_NODES * 64;        // [N]
    int* starts = (int*)(cnt + N_NODES);            // [B+1]
    size_t off = ((size_t)N_NODES * 64 + N_NODES + N_B + 1) * 4;
    off = (off + 15) & ~(size_t)15;
    unsigned short* wt  = (unsigned short*)((char*)d_ws + off);  // 512KB we2 frags
    unsigned short* wtg = wt + 262144;                            // 64KB GRU frags
    float* gbias = (float*)(wtg + 32768);                         // 256 floats
    float4* wA = (float4*)(gbias + 256);                          // 64KB
    float4* wB = wA + 4096;                                       // 64KB
    float* y = (float*)d_out;

    hipMemsetAsync(d_ws, 0, ((size_t)N_NODES * 64 + N_NODES) * sizeof(float), stream);
    k_misc<<<105, 256, 0, stream>>>(we2, wt, gwih, gwhh, gbih, gbhh, wtg, gbias,
                                    lwih, lwhh, wA, wB, batch, starts);
    k_edge<<<1024, 256, 0, stream>>>(x, ea, eidx, we1, be1, wt, be2, buf, cnt, 0);
    k_edge<<<1024, 256, 0, stream>>>(x, ea, eidx, we1, be1, wt, be2, buf, cnt, 1024);
    k_gru2<<<N_NODES / 128, 256, 0, stream>>>(buf, cnt, x, root, cb, wtg, gbias);
    k_s2s<<<N_B / 4, 256, 0, stream>>>(buf, starts, wA, wB, lbih, lbhh,
                                       fc1w, fc1b, fc2w, fc2b, y);
}

// Round 14
// 470.038 us; speedup vs baseline: 1.0787x; 1.0787x over previous
//
#include <hip/hip_runtime.h>
#include <math.h>

#define N_NODES 131072
#define N_EDGES 262144
#define N_B     4096
// NODE_DIM=16, EDGE_DIM=4, HIDDEN=64, MLP_HID=128

typedef __attribute__((ext_vector_type(8))) short short8;
typedef __attribute__((ext_vector_type(4))) float f32x4;
typedef __attribute__((ext_vector_type(16))) float f32x16;

__device__ __forceinline__ float fast_sig(float x) {
    return 1.0f / (1.0f + __expf(-x));
}
__device__ __forceinline__ float fast_tanh(float x) {
    float t = __expf(-2.0f * fabsf(x));
    float r = (1.0f - t) / (1.0f + t);
    return copysignf(r, x);
}

// round-to-nearest-even fp32 -> bf16 (bit trick), plus residual split
__device__ __forceinline__ unsigned short bf16_rne(float v) {
    unsigned u = __float_as_uint(v);
    u += 0x7FFFu + ((u >> 16) & 1u);
    return (unsigned short)(u >> 16);
}
__device__ __forceinline__ void split_bf16(float v, short& hi, short& lo) {
    unsigned short h = bf16_rne(v);
    float hf = __uint_as_float((unsigned)h << 16);
    unsigned short l = bf16_rne(v - hf);
    hi = (short)h; lo = (short)l;
}

// -------- merged prep kernel: blockIdx ranges dispatch the 4 prep jobs -----
__global__ __launch_bounds__(256) void k_misc(
    const float* __restrict__ we2, unsigned short* __restrict__ wt,
    const float* __restrict__ gwih, const float* __restrict__ gwhh,
    const float* __restrict__ gbih, const float* __restrict__ gbhh,
    unsigned short* __restrict__ wtg, float* __restrict__ gbias,
    const float* __restrict__ lwih, const float* __restrict__ lwhh,
    float4* __restrict__ wA, float4* __restrict__ wB,
    const int* __restrict__ batch, int* __restrict__ starts)
{
    const int bid = blockIdx.x;
    const int tid = threadIdx.x;
    if (bid < 64) {
        // ---- prep_w: wt[d(16)][u(2)][s(8)][hl(2)][lane(64)][j(8)] ----
        int p = bid * 256 + tid;  // [0, 16384)
        int d = p >> 10;
        int u = (p >> 9) & 1;
        int s = (p >> 6) & 7;
        int l = p & 63;
        int k0 = s * 16 + ((l >> 5) << 3);
        int h = u * 32 + (l & 31);
        short8 hv, lv;
        #pragma unroll
        for (int j = 0; j < 8; ++j) {
            float v = we2[(size_t)(k0 + j) * 1024 + d * 64 + h];
            short hi, lo; split_bf16(v, hi, lo);
            hv[j] = hi; lv[j] = lo;
        }
        size_t base = (size_t)d * 16384 + (size_t)u * 8192 + s * 1024 + l * 8;
        *(short8*)&wt[base] = hv;
        *(short8*)&wt[base + 512] = lv;
    } else if (bid < 72) {
        // ---- prep_gru ----
        int p = (bid - 64) * 256 + tid;  // [0, 2048)
        if (p < 256) {
            int g = p >> 6, j = p & 63;
            float b;
            if (g == 0)      b = gbih[j] + gbhh[j];
            else if (g == 1) b = gbih[64 + j] + gbhh[64 + j];
            else if (g == 2) b = gbih[128 + j];
            else             b = gbhh[128 + j];
            gbias[p] = b;
        }
        int u = p >> 7, ks = (p >> 6) & 1, ln = p & 63;
        int n = u * 16 + (ln & 15);
        int g = n >> 6, jn = n & 63;
        int k0 = ks * 32 + (ln >> 4) * 8;
        short8 hv, lv;
        #pragma unroll
        for (int jj = 0; jj < 8; ++jj) {
            int k = k0 + jj;
            float v;
            if (g == 0)      v = gwih[jn * 64 + k] + gwhh[jn * 64 + k];
            else if (g == 1) v = gwih[(64 + jn) * 64 + k] + gwhh[(64 + jn) * 64 + k];
            else if (g == 2) v = gwih[(128 + jn) * 64 + k];
            else             v = gwhh[(128 + jn) * 64 + k];
            short hi, lo; split_bf16(v, hi, lo);
            hv[jj] = hi; lv[jj] = lo;
        }
        size_t base = (size_t)(u * 2 + ks) * 1024 + ln * 8;
        *(short8*)&wtg[base] = hv;
        *(short8*)&wtg[base + 512] = lv;
    } else if (bid < 88) {
        // ---- prep_lstm: wA merges wih[:, :64]+whh (q_prev==h_prev) ----
        int p = (bid - 72) * 256 + tid;  // [0, 4096)
        int k = p >> 6, ln = p & 63;
        float4 a, b;
        a.x = lwih[(0 * 64 + ln) * 128 + k] + lwhh[(0 * 64 + ln) * 64 + k];
        a.y = lwih[(1 * 64 + ln) * 128 + k] + lwhh[(1 * 64 + ln) * 64 + k];
        a.z = lwih[(2 * 64 + ln) * 128 + k] + lwhh[(2 * 64 + ln) * 64 + k];
        a.w = lwih[(3 * 64 + ln) * 128 + k] + lwhh[(3 * 64 + ln) * 64 + k];
        b.x = lwih[(0 * 64 + ln) * 128 + 64 + k];
        b.y = lwih[(1 * 64 + ln) * 128 + 64 + k];
        b.z = lwih[(2 * 64 + ln) * 128 + 64 + k];
        b.w = lwih[(3 * 64 + ln) * 128 + 64 + k];
        wA[p] = a; wB[p] = b;
    } else {
        // ---- starts ----
        int g = (bid - 88) * 256 + tid;
        if (g > N_B) return;
        if (g == N_B) { starts[N_B] = N_NODES; return; }
        int lo = 0, hi = N_NODES;
        while (lo < hi) {
            int mid = (lo + hi) >> 1;
            if (batch[mid] < g) lo = mid + 1; else hi = mid;
        }
        starts[g] = lo;
    }
}

// -------- fused edge MLP + 32x32x16 MFMA message GEMM + atomic scatter -----
// (round-12 measured-best version, single dispatch)
__global__ __launch_bounds__(256)
__attribute__((amdgpu_waves_per_eu(2, 2)))
void k_edge(
    const float* __restrict__ x,     // [N,16]
    const float* __restrict__ ea,    // [E,4]
    const int*   __restrict__ eidx,  // [2,E]
    const float* __restrict__ we1,   // [4,128]
    const float* __restrict__ be1,   // [128]
    const unsigned short* __restrict__ wt,  // pre-split we2 frags
    const float* __restrict__ be2,   // [1024]
    float* __restrict__ msum,        // [N,64]
    float* __restrict__ cnt)         // [N]
{
    __shared__ unsigned short sAh[16384];  // [mt(4)][s(8)][lane(64)][j(8)] 32KB
    __shared__ unsigned short sAl[16384];  // 32KB
    __shared__ float sx[128 * 16];         // 8KB
    __shared__ float sbe2[1024];           // 4KB
    __shared__ int   sdst[128];

    const int tid = threadIdx.x;
    const int w   = tid >> 6;        // wave
    const int ln  = tid & 63;        // lane
    const int u     = w >> 1;        // n-tile (cols u*32..u*32+31)
    const int mbase = (w & 1) * 2;   // first of 2 m-tiles
    const int eb  = blockIdx.x * 128;

    if (tid < 128) sdst[tid] = eidx[N_EDGES + eb + tid];
    #pragma unroll
    for (int v = tid; v < 1024; v += 256) sbe2[v] = be2[v];

    #pragma unroll
    for (int v = tid; v < 512; v += 256) {
        int e = v >> 2, q = v & 3;
        int src = eidx[eb + e];
        float4 t4 = ((const float4*)(x + (size_t)src * 16))[q];
        ((float4*)sx)[e * 4 + q] = t4;
    }

    // ---- h1 = relu(ea @ we1 + be1), split bf16 hi/lo, 32x32 A-frag layout --
    #pragma unroll 1
    for (int i = 0; i < 8; ++i) {
        int cc = tid + i * 256;          // [0,2048): [mt(4)][s(8)][l(64)]
        int mt = cc >> 9;
        int s  = (cc >> 6) & 7;
        int l  = cc & 63;
        int e   = mt * 32 + (l & 31);
        int kk0 = s * 16 + ((l >> 5) << 3);
        float4 eav = *(const float4*)(ea + (size_t)(eb + e) * 4);
        float4 b0 = *(const float4*)(be1 + kk0);
        float4 b1 = *(const float4*)(be1 + kk0 + 4);
        float acc[8] = {b0.x, b0.y, b0.z, b0.w, b1.x, b1.y, b1.z, b1.w};
        #pragma unroll
        for (int a = 0; a < 4; ++a) {
            float4 wa0 = *(const float4*)(we1 + a * 128 + kk0);
            float4 wa1 = *(const float4*)(we1 + a * 128 + kk0 + 4);
            float ev = (a == 0) ? eav.x : (a == 1) ? eav.y : (a == 2) ? eav.z : eav.w;
            acc[0] += ev * wa0.x; acc[1] += ev * wa0.y;
            acc[2] += ev * wa0.z; acc[3] += ev * wa0.w;
            acc[4] += ev * wa1.x; acc[5] += ev * wa1.y;
            acc[6] += ev * wa1.z; acc[7] += ev * wa1.w;
        }
        short8 hv, lv;
        #pragma unroll
        for (int j = 0; j < 8; ++j) {
            float v = fmaxf(acc[j], 0.0f);
            short hi, lo; split_bf16(v, hi, lo);
            hv[j] = hi; lv[j] = lo;
        }
        *(short8*)&sAh[cc * 8] = hv;
        *(short8*)&sAl[cc * 8] = lv;
    }
    __syncthreads();   // the ONLY barrier

    // ---- hoist A fragments (compiler keeps hot subset in regs) ----
    short8 ah[2][8], al[2][8];
    #pragma unroll
    for (int m2 = 0; m2 < 2; ++m2) {
        int mt = mbase + m2;
        #pragma unroll
        for (int s = 0; s < 8; ++s) {
            ah[m2][s] = *(short8*)&sAh[((mt * 8 + s) * 64 + ln) * 8];
            al[m2][s] = *(short8*)&sAl[((mt * 8 + s) * 64 + ln) * 8];
        }
    }

    // ---- main loop over d (rotated start); B ring-4, prefetch distance 3 --
    const unsigned short* wdu = wt + (size_t)u * 8192;
    const int d0 = blockIdx.x & 15;
    const int rbase = (ln >> 5) * 4;

    f32x16 msg[2];
    #pragma unroll
    for (int r = 0; r < 16; ++r) { msg[0][r] = 0.0f; msg[1][r] = 0.0f; }

    short8 bh[4], bl[4];
    {   // preload flat steps 0,1,2 of (d0, s)
        const unsigned short* p0 = wdu + (size_t)d0 * 16384 + ln * 8;
        bh[0] = *(const short8*)p0;            bl[0] = *(const short8*)(p0 + 512);
        bh[1] = *(const short8*)(p0 + 1024);   bl[1] = *(const short8*)(p0 + 1536);
        bh[2] = *(const short8*)(p0 + 2048);   bl[2] = *(const short8*)(p0 + 2560);
    }

    #pragma unroll 1
    for (int dd = 0; dd < 16; ++dd) {
        const int d = (d0 + dd) & 15;
        const unsigned short* wd  = wdu + (size_t)d * 16384;
        const unsigned short* wnx = wdu + (size_t)((d + 1) & 15) * 16384;

        float bv = sbe2[d * 64 + u * 32 + (ln & 31)];
        f32x16 c2[2];
        #pragma unroll
        for (int r = 0; r < 16; ++r) { c2[0][r] = bv; c2[1][r] = bv; }

        #pragma unroll
        for (int s = 0; s < 8; ++s) {
            const int cur = s & 3;
            const int pf  = (s + 3) & 3;   // slot freed last step
            if (s < 5) {
                const unsigned short* p = wd + (s + 3) * 1024 + ln * 8;
                bh[pf] = *(const short8*)p;
                bl[pf] = *(const short8*)(p + 512);
            } else if (dd < 15) {
                const unsigned short* p = wnx + (s - 5) * 1024 + ln * 8;
                bh[pf] = *(const short8*)p;
                bl[pf] = *(const short8*)(p + 512);
            }
            c2[0] = __builtin_amdgcn_mfma_f32_32x32x16_bf16(ah[0][s], bh[cur], c2[0], 0, 0, 0);
            c2[1] = __builtin_amdgcn_mfma_f32_32x32x16_bf16(ah[1][s], bh[cur], c2[1], 0, 0, 0);
            c2[0] = __builtin_amdgcn_mfma_f32_32x32x16_bf16(ah[0][s], bl[cur], c2[0], 0, 0, 0);
            c2[1] = __builtin_amdgcn_mfma_f32_32x32x16_bf16(ah[1][s], bl[cur], c2[1], 0, 0, 0);
            c2[0] = __builtin_amdgcn_mfma_f32_32x32x16_bf16(al[0][s], bh[cur], c2[0], 0, 0, 0);
            c2[1] = __builtin_amdgcn_mfma_f32_32x32x16_bf16(al[1][s], bh[cur], c2[1], 0, 0, 0);
        }
        // epilogue: msg += x[:,d] * C_d   (C row = (reg&3)+8*(reg>>2)+rbase)
        #pragma unroll
        for (int m2 = 0; m2 < 2; ++m2) {
            #pragma unroll
            for (int r = 0; r < 16; ++r) {
                int row = (r & 3) + ((r >> 2) * 8) + rbase;
                float xv = sx[((mbase + m2) * 32 + row) * 16 + d];
                msg[m2][r] = fmaf(xv, c2[m2][r], msg[m2][r]);
            }
        }
    }

    // ---- scatter ----
    const int col = u * 32 + (ln & 31);
    #pragma unroll
    for (int m2 = 0; m2 < 2; ++m2) {
        #pragma unroll
        for (int r = 0; r < 16; ++r) {
            int row = (r & 3) + ((r >> 2) * 8) + rbase;
            int dst = sdst[(mbase + m2) * 32 + row];
            atomicAdd(msum + (size_t)dst * 64 + col, msg[m2][r]);
        }
    }
    if (u == 0 && (ln & 31) == 0) {
        #pragma unroll
        for (int m2 = 0; m2 < 2; ++m2) {
            #pragma unroll
            for (int r = 0; r < 16; ++r) {
                int row = (r & 3) + ((r >> 2) * 8) + rbase;
                atomicAdd(&cnt[sdst[(mbase + m2) * 32 + row]], 1.0f);
            }
        }
    }
}

// -------- fused combine + 3-step GRU via in-block MFMA GEMM --------
// (round-12 measured version: 256 nodes/block)
__global__ __launch_bounds__(256, 2) void k_gru2(
    float* __restrict__ buf,        // [N,64] in: msum; out: final h
    const float* __restrict__ cnt,  // [N]
    const float* __restrict__ x,    // [N,16]
    const float* __restrict__ root, // [16,64]
    const float* __restrict__ cb,   // [64]
    const unsigned short* __restrict__ wtg,  // [16][2][2][64][8] ushort
    const float* __restrict__ gbias)         // [256]
{
    __shared__ unsigned short sAh[16384];  // [mt(16)][ks(2)][lane(64)][j(8)] 32KB
    __shared__ unsigned short sAl[16384];  // 32KB
    __shared__ float sroot[1024];
    __shared__ float sbias[256];
    __shared__ float scb[64];
    const int tid = threadIdx.x;
    const int w = tid >> 6, ln = tid & 63, lq = ln >> 4, lm = ln & 15;
    const size_t nbase = (size_t)blockIdx.x * 256;

    #pragma unroll
    for (int v = tid; v < 1024; v += 256) sroot[v] = root[v];
    sbias[tid] = gbias[tid];
    if (tid < 64) scb[tid] = cb[tid];
    __syncthreads();

    // ---- initial A build: combine (msum/cnt + x@root + cb, relu) fused ----
    #pragma unroll 1
    for (int i = 0; i < 8; ++i) {
        int cc = tid + i * 256;            // [mt(16)][ks(2)][l(64)]
        int mt = cc >> 7, ks = (cc >> 6) & 1, l = cc & 63;
        size_t gn = nbase + mt * 16 + (l & 15);
        int c0 = ks * 32 + (l >> 4) * 8;
        float4 m0 = *(const float4*)(buf + gn * 64 + c0);
        float4 m1 = *(const float4*)(buf + gn * 64 + c0 + 4);
        float cinv = 1.0f / fmaxf(cnt[gn], 1.0f);
        float xv[16];
        *(float4*)&xv[0]  = *(const float4*)(x + gn * 16);
        *(float4*)&xv[4]  = *(const float4*)(x + gn * 16 + 4);
        *(float4*)&xv[8]  = *(const float4*)(x + gn * 16 + 8);
        *(float4*)&xv[12] = *(const float4*)(x + gn * 16 + 12);
        float acc[8];
        #pragma unroll
        for (int j = 0; j < 8; ++j) acc[j] = scb[c0 + j];
        #pragma unroll
        for (int d = 0; d < 16; ++d) {
            float xd = xv[d];
            #pragma unroll
            for (int j = 0; j < 8; ++j) acc[j] += xd * sroot[d * 64 + c0 + j];
        }
        float ms[8] = {m0.x, m0.y, m0.z, m0.w, m1.x, m1.y, m1.z, m1.w};
        short8 hv, lv;
        #pragma unroll
        for (int j = 0; j < 8; ++j) {
            float hval = fmaxf(ms[j] * cinv + acc[j], 0.0f);
            short hi, lo; split_bf16(hval, hi, lo);
            hv[j] = hi; lv[j] = lo;
        }
        *(short8*)&sAh[cc * 8] = hv;
        *(short8*)&sAl[cc * 8] = lv;
    }
    __syncthreads();

    float hreg[4][4][4];  // [v][i][reg] old h in C-layout, carried across steps
    #pragma unroll 1
    for (int step = 0; step < 3; ++step) {
        short8 ah[4][2], al[4][2];
        #pragma unroll
        for (int i = 0; i < 4; ++i)
            #pragma unroll
            for (int ks = 0; ks < 2; ++ks) {
                int mt = w * 4 + i;
                ah[i][ks] = *(short8*)&sAh[((mt * 2 + ks) * 64 + ln) * 8];
                al[i][ks] = *(short8*)&sAl[((mt * 2 + ks) * 64 + ln) * 8];
            }
        if (step == 0) {   // old-h at this lane's C positions, once
            #pragma unroll
            for (int v = 0; v < 4; ++v) {
                int ksp = v >> 1;
                int lq2 = (v & 1) * 2 + (lm >> 3);
                int jp = lm & 7;
                #pragma unroll
                for (int i = 0; i < 4; ++i) {
                    int mt = w * 4 + i;
                    #pragma unroll
                    for (int r = 0; r < 4; ++r) {
                        int idx = ((mt * 2 + ksp) * 64 + lq2 * 16 + lq * 4 + r) * 8 + jp;
                        float hi = __uint_as_float((unsigned)sAh[idx] << 16);
                        float lo = __uint_as_float((unsigned)sAl[idx] << 16);
                        hreg[v][i][r] = hi + lo;
                    }
                }
            }
        }
        __syncthreads();   // all reads done before any epilogue write

        #pragma unroll 1
        for (int v = 0; v < 4; ++v) {
            f32x4 C[4][4];  // [gate g][m-tile i]
            #pragma unroll
            for (int g = 0; g < 4; ++g) {
                float bv = sbias[g * 64 + v * 16 + lm];
                #pragma unroll
                for (int i = 0; i < 4; ++i) C[g][i] = (f32x4){bv, bv, bv, bv};
            }
            #pragma unroll
            for (int g = 0; g < 4; ++g) {
                int u = g * 4 + v;
                #pragma unroll
                for (int ks = 0; ks < 2; ++ks) {
                    size_t wb = (size_t)(u * 2 + ks) * 1024 + ln * 8;
                    short8 bh = *(const short8*)&wtg[wb];
                    short8 bl = *(const short8*)&wtg[wb + 512];
                    #pragma unroll
                    for (int i = 0; i < 4; ++i) {
                        C[g][i] = __builtin_amdgcn_mfma_f32_16x16x32_bf16(ah[i][ks], bh, C[g][i], 0, 0, 0);
                        C[g][i] = __builtin_amdgcn_mfma_f32_16x16x32_bf16(ah[i][ks], bl, C[g][i], 0, 0, 0);
                        C[g][i] = __builtin_amdgcn_mfma_f32_16x16x32_bf16(al[i][ks], bh, C[g][i], 0, 0, 0);
                    }
                }
            }
            int ksp = v >> 1;
            int lq2 = (v & 1) * 2 + (lm >> 3);
            int jp = lm & 7;
            #pragma unroll
            for (int i = 0; i < 4; ++i) {
                int mt = w * 4 + i;
                #pragma unroll
                for (int r = 0; r < 4; ++r) {
                    float rr = fast_sig(C[0][i][r]);
                    float zz = fast_sig(C[1][i][r]);
                    float nn = fast_tanh(C[2][i][r] + rr * C[3][i][r]);
                    float hnew = (1.0f - zz) * nn + zz * hreg[v][i][r];
                    hreg[v][i][r] = hnew;
                    if (step < 2) {
                        short hi, lo; split_bf16(hnew, hi, lo);
                        int idx = ((mt * 2 + ksp) * 64 + lq2 * 16 + lq * 4 + r) * 8 + jp;
                        sAh[idx] = (unsigned short)hi;
                        sAl[idx] = (unsigned short)lo;
                    } else {
                        buf[(nbase + mt * 16 + lq * 4 + r) * 64 + v * 16 + lm] = hnew;
                    }
                }
            }
        }
        if (step < 2) __syncthreads();
    }
}

// -------- Set2Set (3 steps) + final MLP; wave-per-graph, 4 graphs/block ----
// First 32 rows of each graph staged into padded LDS (coalesced global read,
// 2-way-free LDS banks); attention a-dot and r_g read LDS; Poisson tail
// (rows >= 32, ~7% of rows) falls back to global for correctness.
__global__ __launch_bounds__(256) void k_s2s(
    const float* __restrict__ out,    // [N,64]
    const int*   __restrict__ starts, // [B+1]
    const float4* __restrict__ wA,    // [64*64] packed gate weights vs h_prev
    const float4* __restrict__ wB,    // [64*64] packed gate weights vs rg_prev
    const float* __restrict__ bih,    // [256]
    const float* __restrict__ bhh,    // [256]
    const float* __restrict__ fc1w,   // [128,64]
    const float* __restrict__ fc1b,   // [64]
    const float* __restrict__ fc2w,   // [64]
    const float* __restrict__ fc2b,   // [1]
    float* __restrict__ y)            // [B]
{
    __shared__ float osh[4][32][66];  // staged rows, +2 pad  (33.8KB)
    __shared__ float qsL[4][128];     // [graph][ h(64) | r_g(64) ]
    __shared__ float ebuf[4][256];
    const int tid = threadIdx.x;
    const int wv = tid >> 6, ln = tid & 63;
    const int gid = blockIdx.x * 4 + wv;

    const int s0 = starts[gid];
    int L = starts[gid + 1] - s0; if (L > 256) L = 256;  // P(L>256) ~ 0 (mean 32)
    const int SL = (L < 32) ? L : 32;                    // staged row count

    // ---- stage first SL rows (coalesced: 16 consecutive lanes = one row) ----
    #pragma unroll
    for (int base = 0; base < 32; base += 4) {
        int row = base + (ln >> 4);
        int c4 = (ln & 15) * 4;
        if (row < SL)
            *(float4*)&osh[wv][row][c4] =
                *(const float4*)(out + (size_t)(s0 + row) * 64 + c4);
    }

    qsL[wv][ln] = 0.0f; qsL[wv][64 + ln] = 0.0f;
    __builtin_amdgcn_wave_barrier();

    const float b0 = bih[ln] + bhh[ln];
    const float b1 = bih[64 + ln] + bhh[64 + ln];
    const float b2 = bih[128 + ln] + bhh[128 + ln];
    const float b3 = bih[192 + ln] + bhh[192 + ln];

    float c = 0.0f;

    #pragma unroll 1
    for (int step = 0; step < 3; ++step) {
        // ---- gates: lane ln = rows {ln, 64+ln, 128+ln, 192+ln} ----
        float a0 = b0, a1 = b1, a2 = b2, a3 = b3;
        #pragma unroll 4
        for (int k = 0; k < 64; ++k) {
            float qk = qsL[wv][k];          // h_prev[k] (== q_prev[k])
            float rk = qsL[wv][64 + k];     // r_g prev[k]
            float4 wa = wA[k * 64 + ln];    // coalesced
            float4 wb = wB[k * 64 + ln];
            a0 += wa.x * qk + wb.x * rk;
            a1 += wa.y * qk + wb.y * rk;
            a2 += wa.z * qk + wb.z * rk;
            a3 += wa.w * qk + wb.w * rk;
        }
        float ig = fast_sig(a0), fg = fast_sig(a1);
        float gg = fast_tanh(a2), og = fast_sig(a3);
        c = fg * c + ig * gg;
        float h = og * fast_tanh(c);
        __builtin_amdgcn_wave_barrier();
        qsL[wv][ln] = h;                    // new q part (wave-private)
        __builtin_amdgcn_wave_barrier();

        // ---- attention: e_j = out[j].h ; staged rows from LDS ----
        float m = -1e30f;
        for (int c0 = 0; c0 * 64 < L; ++c0) {
            int j = c0 * 64 + ln;
            if (j < L) {
                float a = 0.0f;
                if (j < SL) {
                    #pragma unroll
                    for (int l4 = 0; l4 < 16; ++l4) {
                        float4 ov = *(const float4*)&osh[wv][j][l4 * 4];
                        float4 hv = *(const float4*)&qsL[wv][l4 * 4];
                        a += ov.x * hv.x + ov.y * hv.y + ov.z * hv.z + ov.w * hv.w;
                    }
                } else {
                    const float4* orow = (const float4*)(out + (size_t)(s0 + j) * 64);
                    #pragma unroll
                    for (int l4 = 0; l4 < 16; ++l4) {
                        float4 ov = orow[l4];
                        float4 hv = *(const float4*)&qsL[wv][l4 * 4];
                        a += ov.x * hv.x + ov.y * hv.y + ov.z * hv.z + ov.w * hv.w;
                    }
                }
                ebuf[wv][j] = a;
                m = fmaxf(m, a);
            }
        }
        #pragma unroll
        for (int off = 32; off; off >>= 1) m = fmaxf(m, __shfl_xor(m, off));
        float ds = 0.0f;
        for (int c0 = 0; c0 * 64 < L; ++c0) {
            int j = c0 * 64 + ln;
            if (j < L) {
                float ex = __expf(ebuf[wv][j] - m);
                ebuf[wv][j] = ex;
                ds += ex;
            }
        }
        #pragma unroll
        for (int off = 32; off; off >>= 1) ds += __shfl_xor(ds, off);
        __builtin_amdgcn_wave_barrier();
        // r_g[ln] = sum_j a_j * out[s0+j][ln]
        float rg = 0.0f;
        for (int j = 0; j < SL; ++j)
            rg = fmaf(ebuf[wv][j], osh[wv][j][ln], rg);
        for (int j = SL; j < L; ++j)
            rg = fmaf(ebuf[wv][j], out[(size_t)(s0 + j) * 64 + ln], rg);
        rg = (L > 0) ? (rg / ds) : 0.0f;
        qsL[wv][64 + ln] = rg;
        __builtin_amdgcn_wave_barrier();
    }

    // ---- final MLP: u = relu(q_star@fc1 + b); y = u@fc2 + b2 ----
    float a = fc1b[ln];
    #pragma unroll 4
    for (int k = 0; k < 128; ++k)
        a = fmaf(qsL[wv][k], fc1w[k * 64 + ln], a);
    float uu = fmaxf(a, 0.0f) * fc2w[ln];
    #pragma unroll
    for (int off = 32; off; off >>= 1) uu += __shfl_xor(uu, off);
    if (ln == 0) y[gid] = uu + fc2b[0];
}

extern "C" void kernel_launch(void* const* d_in, const int* in_sizes, int n_in,
                              void* d_out, int out_size, void* d_ws, size_t ws_size,
                              hipStream_t stream) {
    const float* x     = (const float*)d_in[0];
    const float* ea    = (const float*)d_in[1];
    const int*   eidx  = (const int*)d_in[2];
    const int*   batch = (const int*)d_in[3];
    const float* we1   = (const float*)d_in[4];
    const float* be1   = (const float*)d_in[5];
    const float* we2   = (const float*)d_in[6];
    const float* be2   = (const float*)d_in[7];
    const float* root  = (const float*)d_in[8];
    const float* cb    = (const float*)d_in[9];
    const float* gwih  = (const float*)d_in[10];
    const float* gwhh  = (const float*)d_in[11];
    const float* gbih  = (const float*)d_in[12];
    const float* gbhh  = (const float*)d_in[13];
    const float* lwih  = (const float*)d_in[14];
    const float* lwhh  = (const float*)d_in[15];
    const float* lbih  = (const float*)d_in[16];
    const float* lbhh  = (const float*)d_in[17];
    const float* fc1w  = (const float*)d_in[18];
    const float* fc1b  = (const float*)d_in[19];
    const float* fc2w  = (const float*)d_in[20];
    const float* fc2b  = (const float*)d_in[21];

    float* buf = (float*)d_ws;                      // [N,64] msum -> h
    float* cnt = buf + (size_t)N_NODES * 64;        // [N]
    int* starts = (int*)(cnt + N_NODES);            // [B+1]
    size_t off = ((size_t)N_NODES * 64 + N_NODES + N_B + 1) * 4;
    off = (off + 15) & ~(size_t)15;
    unsigned short* wt  = (unsigned short*)((char*)d_ws + off);  // 512KB we2 frags
    unsigned short* wtg = wt + 262144;                            // 64KB GRU frags
    float* gbias = (float*)(wtg + 32768);                         // 256 floats
    float4* wA = (float4*)(gbias + 256);                          // 64KB
    float4* wB = wA + 4096;                                       // 64KB
    float* y = (float*)d_out;

    hipMemsetAsync(d_ws, 0, ((size_t)N_NODES * 64 + N_NODES) * sizeof(float), stream);
    k_misc<<<105, 256, 0, stream>>>(we2, wt, gwih, gwhh, gbih, gbhh, wtg, gbias,
                                    lwih, lwhh, wA, wB, batch, starts);
    k_edge<<<N_EDGES / 128, 256, 0, stream>>>(x, ea, eidx, we1, be1, wt, be2, buf, cnt);
    k_gru2<<<N_NODES / 256, 256, 0, stream>>>(buf, cnt, x, root, cb, wtg, gbias);
    k_s2s<<<N_B / 4, 256, 0, stream>>>(buf, starts, wA, wB, lbih, lbhh,
                                       fc1w, fc1b, fc2w, fc2b, y);
}